// Round 10
// baseline (269.931 us; speedup 1.0000x reference)
//
#include <hip/hip_runtime.h>
#include <stdint.h>

#define B_  32
#define CIN 64
#define H_  56
#define W_  56
#define HW_ 3136
#define P_  384
#define CO_ 96

typedef unsigned short u16;
typedef short v2s __attribute__((ext_vector_type(2)));

__device__ __forceinline__ v2s as_v2s(int x) {
    union { int i; v2s v; } u; u.i = x; return u.v;
}

// exp2(ceil(log2(max(m,1e-8)/n))) computed exactly (handles pot boundary via frexp)
__device__ __forceinline__ float pot_scale(float m, float n) {
    float q = fmaxf(m, 1e-8f) / n;
    int e; float f = frexpf(q, &e);        // q = f*2^e, f in [0.5,1)
    return ldexpf(1.0f, (f == 0.5f) ? (e - 1) : e);
}

// signed 8x int4 dot product (v_dot8_i32_i4)
__device__ __forceinline__ int dot8(int a, int b, int c) {
#if __has_builtin(__builtin_amdgcn_sdot8)
    return __builtin_amdgcn_sdot8(a, b, c, false);
#else
#pragma unroll
    for (int j = 0; j < 8; j++) {
        int av = (a << (28 - 4 * j)) >> 28;
        int bv = (b << (28 - 4 * j)) >> 28;
        c += av * bv;
    }
    return c;
#endif
}

__device__ __forceinline__ int iclamp(int v, int lo, int hi) { return min(max(v, lo), hi); }

// 16-entry level->level LUT (q = min(rint(L*r),7)) packed into two regs, 4b/entry.
__device__ __forceinline__ unsigned build_lut(float r, int lo) {
    unsigned v = 0;
#pragma unroll
    for (int L = 0; L < 8; L++)
        v |= (unsigned)min((int)rintf(__fmul_rn((float)(lo + L), r)), 7) << (4 * L);
    return v;
}
__device__ __forceinline__ int lut1(unsigned lo, unsigned hi, int L) {
    unsigned sel = (L & 8) ? hi : lo;
    return (int)((sel >> ((L & 7) * 4)) & 7u);
}

__device__ __forceinline__ int wave_max(int v) {
#pragma unroll
    for (int off = 32; off > 0; off >>= 1) v = max(v, __shfl_xor(v, off, 64));
    return v;
}
// block max over nw waves (v >= 0); red has >= (slot+1)*8 slots; 1 barrier
__device__ __forceinline__ int block_max_w(int v, int* red, int slot, int nw) {
    v = wave_max(v);
    int wid = threadIdx.x >> 6;
    if ((threadIdx.x & 63) == 0) red[slot * 8 + wid] = v;
    __syncthreads();
    int r = red[slot * 8];
#pragma unroll 4
    for (int i = 1; i < nw; i++) r = max(r, red[slot * 8 + i]);
    return r;
}

// sf[0]=max|x|, sf[1..4]=max|w1,w2,w3,ws|   (zeroed by hipMemsetAsync)
// smax (4KB, zeroed): quantity q at smax[q*256 + slot*16], slot in [0,16)
//   q=0: maxL1   q=1: maxL2   q=2: maxAcc3   q=3: maxAccS
#define SMAX_RD(sm, q, dst) { dst = 0; _Pragma("unroll") \
    for (int s_ = 0; s_ < 16; s_++) dst = max(dst, (sm)[(q) * 256 + s_ * 16]); }

#define XBLK 384
// x/w abs-max scan + BN constant precompute (bn blocks are independent of sf)
// bnb: inv1[0:384] beta1[384:768] inv2[768:1152] beta2[1152:1536]
//      inv3[1536:1632] beta3[1632:1728] invs[1728:1824] betas[1824:1920]
__global__ __launch_bounds__(256) void k_maxes(
    const float* __restrict__ x, const float* __restrict__ w1,
    const float* __restrict__ w2, const float* __restrict__ w3,
    const float* __restrict__ wsc, float* sf, float* bnb,
    const float* g1, const float* b1, const float* m1, const float* v1,
    const float* g2, const float* b2, const float* m2, const float* v2,
    const float* g3, const float* b3, const float* m3, const float* v3,
    const float* gs, const float* bs, const float* ms, const float* vs)
{
    __shared__ int red[16];
    int tid = threadIdx.x;
    if (blockIdx.x >= XBLK + 4) {                    // 4 bn-init blocks
        int t = (blockIdx.x - XBLK - 4) * 256 + tid; // 0..1023
        if (t < 384) {
            float inv = __fmul_rn(g1[t], __fdiv_rn(1.0f, sqrtf(__fadd_rn(v1[t], 1e-5f))));
            bnb[t] = inv;
            bnb[384 + t] = __fsub_rn(b1[t], __fmul_rn(m1[t], inv));
        } else if (t < 768) {
            int i = t - 384;
            float inv = __fmul_rn(g2[i], __fdiv_rn(1.0f, sqrtf(__fadd_rn(v2[i], 1e-5f))));
            bnb[768 + i] = inv;
            bnb[1152 + i] = __fsub_rn(b2[i], __fmul_rn(m2[i], inv));
        } else if (t < 864) {
            int i = t - 768;
            float inv = __fmul_rn(g3[i], __fdiv_rn(1.0f, sqrtf(__fadd_rn(v3[i], 1e-5f))));
            bnb[1536 + i] = inv;
            bnb[1632 + i] = __fsub_rn(b3[i], __fmul_rn(m3[i], inv));
        } else if (t < 960) {
            int i = t - 864;
            float inv = __fmul_rn(gs[i], __fdiv_rn(1.0f, sqrtf(__fadd_rn(vs[i], 1e-5f))));
            bnb[1728 + i] = inv;
            bnb[1824 + i] = __fsub_rn(bs[i], __fmul_rn(ms[i], inv));
        }
        return;
    }
    float m = 0.f;
    if (blockIdx.x < XBLK) {
        const float4* x4 = (const float4*)x;
        const int n4 = (B_ * CIN * HW_) / 4;   // 1605632
        for (int i = blockIdx.x * 256 + tid; i < n4; i += XBLK * 256) {
            float4 v = x4[i];
            m = fmaxf(m, fmaxf(fmaxf(fabsf(v.x), fabsf(v.y)),
                               fmaxf(fabsf(v.z), fabsf(v.w))));
        }
        int bm = block_max_w(__float_as_int(m), red, 0, 4);
        if (tid == 0) atomicMax((int*)&sf[0], bm);
    } else {
        int seg = blockIdx.x - XBLK;
        const float* p = seg == 0 ? w1 : seg == 1 ? w2 : seg == 2 ? w3 : wsc;
        int n = seg == 0 ? P_ * CIN : seg == 1 ? P_ * 9 : seg == 2 ? CO_ * P_ : CO_ * CIN;
        for (int i = tid; i < n; i += 256) m = fmaxf(m, fabsf(p[i]));
        int bm = block_max_w(__float_as_int(m), red, 0, 4);
        if (tid == 0) atomicMax((int*)&sf[1 + seg], bm);
    }
}

// weight quant + nibble repack (layouts unchanged)
__global__ __launch_bounds__(256) void k_quantw(
    const float* __restrict__ w1, const float* __restrict__ w2,
    const float* __restrict__ w3, const float* __restrict__ wsc,
    const float* __restrict__ sf,
    int* __restrict__ w1n, int8_t* __restrict__ w2q,
    int* __restrict__ w3n, int* __restrict__ wsn)
{
    int flat = blockIdx.x * 256 + threadIdx.x;
    if (flat < 3072) {                               // w1n
        int d = flat, co = d & 3, k8 = (d >> 2) & 7, g = d >> 5;
        float r = 1.0f / pot_scale(sf[1], 7.f);
        const float* src = w1 + (4 * g + co) * 64 + 8 * k8;
        unsigned pk = 0;
#pragma unroll
        for (int j = 0; j < 8; j++) {
            int q = iclamp((int)rintf(__fmul_rn(src[j], r)), -8, 7);
            pk |= (unsigned)(q & 0xF) << (4 * j);
        }
        w1n[d] = (int)pk;
    } else if (flat < 7680) {                        // w3n
        int d = flat - 3072, co = d & 3, k8 = (d >> 2) % 48, coq = d / 192;
        float r = 1.0f / pot_scale(sf[3], 7.f);
        const float* src = w3 + (4 * coq + co) * 384 + 8 * k8;
        unsigned pk = 0;
#pragma unroll
        for (int j = 0; j < 8; j++) {
            int q = iclamp((int)rintf(__fmul_rn(src[j], r)), -8, 7);
            pk |= (unsigned)(q & 0xF) << (4 * j);
        }
        w3n[d] = (int)pk;
    } else if (flat < 8448) {                        // wsn
        int d = flat - 7680, co = d & 3, k8 = (d >> 2) & 7, coq = d >> 5;
        float r = 1.0f / pot_scale(sf[4], 7.f);
        const float* src = wsc + (4 * coq + co) * 64 + 8 * k8;
        unsigned pk = 0;
#pragma unroll
        for (int j = 0; j < 8; j++) {
            int q = iclamp((int)rintf(__fmul_rn(src[j], r)), -8, 7);
            pk |= (unsigned)(q & 0xF) << (4 * j);
        }
        wsn[d] = (int)pk;
    } else if (flat < 11904) {                       // w2: [384*9] int8
        int i = flat - 8448;
        float r = 1.0f / pot_scale(sf[2], 7.f);
        w2q[i] = (int8_t)iclamp((int)rintf(__fmul_rn(w2[i], r)), -8, 7);
    }
}

// expand 1x1 (64->384) + BN1 + QuantReLU4 -> nibble-level out1h[b][96][hw]
// 2 h-rows per block (896 blocks, all co-resident). Fused x-quant + shortcut amax.
__global__ __launch_bounds__(192) void k_conv1(
    const float* __restrict__ x, const int4* __restrict__ w1n,
    const int4* __restrict__ wsn,
    const float* __restrict__ sf, const float* __restrict__ bnb,
    u16* __restrict__ out1h, int* __restrict__ xq4, int* smax)
{
    __shared__ __align__(16) int xs[2 * 8 * W_];     // 3.5KB
    __shared__ __align__(16) u16 otile[2 * 96 * W_]; // 21KB
    __shared__ int red[16];
    int tid = threadIdx.x;
    int b = blockIdx.x / 28, h0 = (blockIdx.x % 28) * 2;
    float rx = 1.0f / pot_scale(sf[0], 7.0f);
    for (int i = tid; i < 224; i += 192) {           // (row, c8, w4) float4 tasks
        int row = i / 112, rem = i % 112, c8 = rem / 14, w4 = (rem % 14) * 4;
        const float* xp = x + (size_t)(b * 64 + c8 * 8) * HW_ + (h0 + row) * W_ + w4;
        unsigned pk[4] = {0, 0, 0, 0};
#pragma unroll
        for (int j = 0; j < 8; j++) {
            float4 v = *(const float4*)(xp + (size_t)j * HW_);
            float va[4] = {v.x, v.y, v.z, v.w};
#pragma unroll
            for (int w = 0; w < 4; w++) {
                int q = iclamp((int)rintf(__fmul_rn(va[w], rx)), -8, 7);
                pk[w] |= (unsigned)(q & 0xF) << (4 * j);
            }
        }
        int4 st = make_int4((int)pk[0], (int)pk[1], (int)pk[2], (int)pk[3]);
        *(int4*)&xs[row * 8 * W_ + c8 * W_ + w4] = st;
        *(int4*)(xq4 + (size_t)(b * 8 + c8) * HW_ + (h0 + row) * W_ + w4) = st;
    }
    float sprod = __fmul_rn(pot_scale(sf[0], 7.f), pot_scale(sf[1], 7.f));
    __syncthreads();
    int g = tid % 96, half = tid / 96;               // half in {0,1}
    int4 wreg[8];
    {
        const int4* wp = w1n + g * 8;
#pragma unroll
        for (int k = 0; k < 8; k++) wreg[k] = wp[k];
    }
    float4 invv = *(const float4*)&bnb[4 * g];
    float4 betv = *(const float4*)&bnb[384 + 4 * g];
    float inva[4] = {invv.x, invv.y, invv.z, invv.w};
    float beta[4] = {betv.x, betv.y, betv.z, betv.w};
    int lmax = 0;
#pragma unroll
    for (int row = 0; row < 2; row++) {
        const int* xrow = xs + row * 8 * W_;
        u16* orow = otile + row * 96 * W_;
#pragma unroll
        for (int q = 0; q < 7; q++) {
            int w4 = half * 28 + q * 4;
            int acc[4][4];                           // [co][w]
#pragma unroll
            for (int c = 0; c < 4; c++)
#pragma unroll
                for (int w = 0; w < 4; w++) acc[c][w] = 0;
#pragma unroll
            for (int k = 0; k < 8; k++) {
                int4 wv = wreg[k];
                int4 xv = *(const int4*)&xrow[k * W_ + w4];
                acc[0][0] = dot8(xv.x, wv.x, acc[0][0]); acc[0][1] = dot8(xv.y, wv.x, acc[0][1]);
                acc[0][2] = dot8(xv.z, wv.x, acc[0][2]); acc[0][3] = dot8(xv.w, wv.x, acc[0][3]);
                acc[1][0] = dot8(xv.x, wv.y, acc[1][0]); acc[1][1] = dot8(xv.y, wv.y, acc[1][1]);
                acc[1][2] = dot8(xv.z, wv.y, acc[1][2]); acc[1][3] = dot8(xv.w, wv.y, acc[1][3]);
                acc[2][0] = dot8(xv.x, wv.z, acc[2][0]); acc[2][1] = dot8(xv.y, wv.z, acc[2][1]);
                acc[2][2] = dot8(xv.z, wv.z, acc[2][2]); acc[2][3] = dot8(xv.w, wv.z, acc[2][3]);
                acc[3][0] = dot8(xv.x, wv.w, acc[3][0]); acc[3][1] = dot8(xv.y, wv.w, acc[3][1]);
                acc[3][2] = dot8(xv.z, wv.w, acc[3][2]); acc[3][3] = dot8(xv.w, wv.w, acc[3][3]);
            }
            unsigned lv[4];
#pragma unroll
            for (int w = 0; w < 4; w++) {
                unsigned pkd = 0;
#pragma unroll
                for (int c = 0; c < 4; c++) {
                    float y = __fadd_rn(__fmul_rn(__fmul_rn((float)acc[c][w], sprod), inva[c]), beta[c]);
                    int L = iclamp((int)rintf(__fmul_rn(y, 4.f)), 0, 15);
                    lmax = max(lmax, L);
                    pkd |= (unsigned)L << (4 * c);
                }
                lv[w] = pkd;
            }
            *(uint2*)&orow[g * W_ + w4] =
                make_uint2(lv[0] | (lv[1] << 16), lv[2] | (lv[3] << 16));
        }
    }
    __syncthreads();
    // cooperative coalesced store: 7 lanes cover one g row (112B)
    {
        for (int i = tid; i < 2 * 96 * 7; i += 192) {
            int row = i / 672, rem = i % 672, gg = rem / 7, wq = (rem % 7) * 8;
            *(uint4*)(out1h + (size_t)(b * 96 + gg) * HW_ + (h0 + row) * W_ + wq) =
                *(uint4*)&otile[row * 96 * W_ + gg * W_ + wq];
        }
    }
    int bm = block_max_w(lmax, red, 0, 3);
    if (tid == 0) atomicMax(&smax[0 * 256 + (blockIdx.x & 15) * 16], bm);
    // fused shortcut 1x1 amax (values recomputed in k_final)
    int amax = 0;
    for (int qi = tid; qi < 672; qi += 192) {
        int row = qi / 336, rem = qi % 336, coq = rem / 14, w4 = (rem % 14) * 4;
        const int* xrow = xs + row * 8 * W_;
        int acc[4][4];
#pragma unroll
        for (int c = 0; c < 4; c++)
#pragma unroll
            for (int w = 0; w < 4; w++) acc[c][w] = 0;
        const int4* wp = wsn + coq * 8;
#pragma unroll
        for (int k = 0; k < 8; k++) {
            int4 wv = wp[k];
            int4 xv = *(const int4*)&xrow[k * W_ + w4];
            acc[0][0] = dot8(xv.x, wv.x, acc[0][0]); acc[0][1] = dot8(xv.y, wv.x, acc[0][1]);
            acc[0][2] = dot8(xv.z, wv.x, acc[0][2]); acc[0][3] = dot8(xv.w, wv.x, acc[0][3]);
            acc[1][0] = dot8(xv.x, wv.y, acc[1][0]); acc[1][1] = dot8(xv.y, wv.y, acc[1][1]);
            acc[1][2] = dot8(xv.z, wv.y, acc[1][2]); acc[1][3] = dot8(xv.w, wv.y, acc[1][3]);
            acc[2][0] = dot8(xv.x, wv.z, acc[2][0]); acc[2][1] = dot8(xv.y, wv.z, acc[2][1]);
            acc[2][2] = dot8(xv.z, wv.z, acc[2][2]); acc[2][3] = dot8(xv.w, wv.z, acc[2][3]);
            acc[3][0] = dot8(xv.x, wv.w, acc[3][0]); acc[3][1] = dot8(xv.y, wv.w, acc[3][1]);
            acc[3][2] = dot8(xv.z, wv.w, acc[3][2]); acc[3][3] = dot8(xv.w, wv.w, acc[3][3]);
        }
#pragma unroll
        for (int c = 0; c < 4; c++)
            amax = max(amax, max(max(abs(acc[c][0]), abs(acc[c][1])),
                                 max(abs(acc[c][2]), abs(acc[c][3]))));
    }
    bm = block_max_w(amax, red, 1, 3);
    if (tid == 0) atomicMax(&smax[3 * 256 + (blockIdx.x & 15) * 16], bm);
}

// depthwise 3x3 + BN2 + QuantReLU4; packed-i16 channel-pair MACs (v_pk ops)
__global__ __launch_bounds__(256) void k_conv2(
    const u16* __restrict__ out1h, const int8_t* __restrict__ w2q,
    const float* __restrict__ sf, int* smax,
    const float* __restrict__ bnb, u16* __restrict__ out2h)
{
    __shared__ int blut[256];                        // byte -> packed pair (i16 lanes)
    __shared__ __align__(8) int plane2[58 * 58 * 2]; // 26.9KB: [pix][pair]
    __shared__ int red[16];
    int tid = threadIdx.x;
    int b = blockIdx.x / 96, g = blockIdx.x % 96;
    int mL1; SMAX_RD(smax, 0, mL1);
    float s_a2 = pot_scale(0.25f * (float)mL1, 7.f);
    float r2 = 0.25f / s_a2;                         // exact pot ratio
    float sprod = __fmul_rn(s_a2, pot_scale(sf[2], 7.f));
    unsigned lutlo = build_lut(r2, 0), luthi = build_lut(r2, 8);
    blut[tid] = (lut1(lutlo, luthi, tid & 0xF) & 0xFFFF)
              | (lut1(lutlo, luthi, tid >> 4) << 16);
    int wv[4][9];
#pragma unroll
    for (int c = 0; c < 4; c++)
#pragma unroll
        for (int t = 0; t < 9; t++) wv[c][t] = (int)w2q[(4 * g + c) * 9 + t];
    int wpk[2][9];
#pragma unroll
    for (int p = 0; p < 2; p++)
#pragma unroll
        for (int t = 0; t < 9; t++)
            wpk[p][t] = (wv[2 * p][t] & 0xFFFF) | (wv[2 * p + 1][t] << 16);
    float4 invv = *(const float4*)&bnb[768 + 4 * g];
    float4 betv = *(const float4*)&bnb[1152 + 4 * g];
    float inva[4] = {invv.x, invv.y, invv.z, invv.w};
    float beta[4] = {betv.x, betv.y, betv.z, betv.w};
    __syncthreads();
    const u16* src = out1h + (size_t)(b * 96 + g) * HW_;
    for (int i = tid; i < 58 * 58; i += 256) {
        int r = i / 58, c = i % 58;
        int pv0 = 0, pv1 = 0;
        if (r >= 1 && r <= 56 && c >= 1 && c <= 56) {
            unsigned v = src[(r - 1) * W_ + (c - 1)];
            pv0 = blut[v & 0xFFu];
            pv1 = blut[(v >> 8) & 0xFFu];
        }
        *(int2*)&plane2[2 * i] = make_int2(pv0, pv1);
    }
    __syncthreads();
    int lmax = 0;
    int ow = tid & 63, seg = tid >> 6;               // 4 segs x 14 rows
    if (ow < 56) {
        int oh0 = seg * 14;
        const int2* pl = (const int2*)plane2;
        u16* dst = out2h + (size_t)(b * 96 + g) * HW_ + ow;
        int2 p00 = pl[oh0 * 58 + ow],       p01 = pl[oh0 * 58 + ow + 1],       p02 = pl[oh0 * 58 + ow + 2];
        int2 p10 = pl[(oh0 + 1) * 58 + ow], p11 = pl[(oh0 + 1) * 58 + ow + 1], p12 = pl[(oh0 + 1) * 58 + ow + 2];
#pragma unroll 2
        for (int oh = oh0; oh < oh0 + 14; oh++) {
            int2 p20 = pl[(oh + 2) * 58 + ow], p21 = pl[(oh + 2) * 58 + ow + 1],
                 p22 = pl[(oh + 2) * 58 + ow + 2];
            v2s a0 = as_v2s(p00.x) * as_v2s(wpk[0][0]);
            a0 += as_v2s(p01.x) * as_v2s(wpk[0][1]);
            a0 += as_v2s(p02.x) * as_v2s(wpk[0][2]);
            a0 += as_v2s(p10.x) * as_v2s(wpk[0][3]);
            a0 += as_v2s(p11.x) * as_v2s(wpk[0][4]);
            a0 += as_v2s(p12.x) * as_v2s(wpk[0][5]);
            a0 += as_v2s(p20.x) * as_v2s(wpk[0][6]);
            a0 += as_v2s(p21.x) * as_v2s(wpk[0][7]);
            a0 += as_v2s(p22.x) * as_v2s(wpk[0][8]);
            v2s a1 = as_v2s(p00.y) * as_v2s(wpk[1][0]);
            a1 += as_v2s(p01.y) * as_v2s(wpk[1][1]);
            a1 += as_v2s(p02.y) * as_v2s(wpk[1][2]);
            a1 += as_v2s(p10.y) * as_v2s(wpk[1][3]);
            a1 += as_v2s(p11.y) * as_v2s(wpk[1][4]);
            a1 += as_v2s(p12.y) * as_v2s(wpk[1][5]);
            a1 += as_v2s(p20.y) * as_v2s(wpk[1][6]);
            a1 += as_v2s(p21.y) * as_v2s(wpk[1][7]);
            a1 += as_v2s(p22.y) * as_v2s(wpk[1][8]);
            int acca[4] = {(int)a0.x, (int)a0.y, (int)a1.x, (int)a1.y};
            unsigned pkd = 0;
#pragma unroll
            for (int c = 0; c < 4; c++) {
                float y = __fadd_rn(__fmul_rn(__fmul_rn((float)acca[c], sprod), inva[c]), beta[c]);
                int L = iclamp((int)rintf(__fmul_rn(y, 4.f)), 0, 15);
                lmax = max(lmax, L);
                pkd |= (unsigned)L << (4 * c);
            }
            dst[oh * W_] = (u16)pkd;
            p00 = p10; p01 = p11; p02 = p12;
            p10 = p20; p11 = p21; p12 = p22;
        }
    }
    int bm = block_max_w(lmax, red, 0, 4);
    if (tid == 0) atomicMax(&smax[1 * 256 + (blockIdx.x & 15) * 16], bm);
}

// project 1x1 (384->96): nibble dot8; 2 rows/block; int16 acc out
__global__ __launch_bounds__(256) void k_conv3(
    const u16* __restrict__ out2h, const int4* __restrict__ w3n,
    const float* __restrict__ sf, int* smax,
    int16_t* __restrict__ acc3)
{
    __shared__ __align__(16) int a3s[2 * 48 * W_];   // 21.5KB nibble-packed
    __shared__ int nlut[256];                        // byte -> 2 quant nibbles
    __shared__ int red[16];
    int tid = threadIdx.x;
    int b = blockIdx.x / 28, h0 = (blockIdx.x % 28) * 2;
    int mL2; SMAX_RD(smax, 1, mL2);
    float s_a3 = pot_scale(0.25f * (float)mL2, 7.f);
    float r3 = 0.25f / s_a3;
    unsigned lutlo = build_lut(r3, 0), luthi = build_lut(r3, 8);
    nlut[tid] = lut1(lutlo, luthi, tid & 0xF) | (lut1(lutlo, luthi, tid >> 4) << 4);
    __syncthreads();
    for (int i = tid; i < 2 * 48 * W_; i += 256) {   // 5376 = 21*256 exact
        int row = i / (48 * W_), rem = i % (48 * W_), c8 = rem / W_, w = rem % W_;
        size_t base = (size_t)(b * 96 + c8 * 2) * HW_ + (h0 + row) * W_ + w;
        unsigned v0 = out2h[base], v1 = out2h[base + HW_];
        unsigned q0 = (unsigned)nlut[v0 & 0xFFu] | ((unsigned)nlut[(v0 >> 8) & 0xFFu] << 8);
        unsigned q1 = (unsigned)nlut[v1 & 0xFFu] | ((unsigned)nlut[(v1 >> 8) & 0xFFu] << 8);
        a3s[i] = (int)(q0 | (q1 << 16));
    }
    __syncthreads();
    int amax = 0;
    for (int qi = tid; qi < 672; qi += 256) {        // coq(24) x row(2) x w4(14)
        int coq = qi / 28, rem2 = qi % 28, row = rem2 / 14, w4 = (rem2 % 14) * 4;
        int acc[4][4];                               // [co][w]
#pragma unroll
        for (int c = 0; c < 4; c++)
#pragma unroll
            for (int w = 0; w < 4; w++) acc[c][w] = 0;
        const int4* wp = w3n + coq * 48;
        const int* ap = a3s + row * 48 * W_ + w4;
#pragma unroll 6
        for (int k = 0; k < 48; k++) {
            int4 wv = wp[k];
            int4 av = *(const int4*)(ap + k * W_);
            acc[0][0] = dot8(av.x, wv.x, acc[0][0]); acc[0][1] = dot8(av.y, wv.x, acc[0][1]);
            acc[0][2] = dot8(av.z, wv.x, acc[0][2]); acc[0][3] = dot8(av.w, wv.x, acc[0][3]);
            acc[1][0] = dot8(av.x, wv.y, acc[1][0]); acc[1][1] = dot8(av.y, wv.y, acc[1][1]);
            acc[1][2] = dot8(av.z, wv.y, acc[1][2]); acc[1][3] = dot8(av.w, wv.y, acc[1][3]);
            acc[2][0] = dot8(av.x, wv.z, acc[2][0]); acc[2][1] = dot8(av.y, wv.z, acc[2][1]);
            acc[2][2] = dot8(av.z, wv.z, acc[2][2]); acc[2][3] = dot8(av.w, wv.z, acc[2][3]);
            acc[3][0] = dot8(av.x, wv.w, acc[3][0]); acc[3][1] = dot8(av.y, wv.w, acc[3][1]);
            acc[3][2] = dot8(av.z, wv.w, acc[3][2]); acc[3][3] = dot8(av.w, wv.w, acc[3][3]);
        }
#pragma unroll
        for (int c = 0; c < 4; c++) {
            int co = coq * 4 + c;
            amax = max(amax, max(max(abs(acc[c][0]), abs(acc[c][1])),
                                 max(abs(acc[c][2]), abs(acc[c][3]))));
            short4 st = make_short4((short)acc[c][0], (short)acc[c][1],
                                    (short)acc[c][2], (short)acc[c][3]);
            *(short4*)(acc3 + (size_t)(b * CO_ + co) * HW_ + (h0 + row) * W_ + w4) = st;
        }
    }
    int bm = block_max_w(amax, red, 0, 4);
    if (tid == 0) atomicMax(&smax[2 * 256 + (blockIdx.x & 15) * 16], bm);
}

// fq8(conv3)+BN3 + fq4(shortcut)+BNs + add + QuantReLU4 -> fp32 out
__global__ __launch_bounds__(256) void k_final(
    const int* __restrict__ xq4, const int4* __restrict__ wsn,
    const int16_t* __restrict__ acc3, const float* __restrict__ sf,
    const int* __restrict__ smax, const float* __restrict__ bnb,
    float* __restrict__ dout)
{
    __shared__ __align__(16) int xs[8 * W_];
    int tid = threadIdx.x;
    int b = blockIdx.x / H_, h = blockIdx.x % H_;
    for (int i = tid; i < 8 * W_; i += 256)
        xs[i] = xq4[((b * 8 + i / W_) * HW_) + h * W_ + (i % W_)];
    int mL2, mA3, mAS;
    SMAX_RD(smax, 1, mL2); SMAX_RD(smax, 2, mA3); SMAX_RD(smax, 3, mAS);
    float s_a3   = pot_scale(0.25f * (float)mL2, 7.f);
    float sprod3 = __fmul_rn(s_a3, pot_scale(sf[3], 7.f));
    float s_q3   = pot_scale(__fmul_rn(sprod3, (float)mA3), 127.f);
    float rq3    = sprod3 / s_q3;                    // exact pot ratio
    float sprods = __fmul_rn(pot_scale(sf[0], 7.f), pot_scale(sf[4], 7.f));
    float s_qs   = pot_scale(__fmul_rn(sprods, (float)mAS), 7.f);
    float rqs    = sprods / s_qs;
    __syncthreads();
    for (int qi = tid; qi < 24 * 14; qi += 256) {    // 336 tiles
        int coq = qi / 14, w4 = (qi % 14) * 4;
        int acc[4][4];
#pragma unroll
        for (int c = 0; c < 4; c++)
#pragma unroll
            for (int w = 0; w < 4; w++) acc[c][w] = 0;
        const int4* wp = wsn + coq * 8;
#pragma unroll
        for (int k = 0; k < 8; k++) {
            int4 wv = wp[k];
            int4 xv = *(const int4*)&xs[k * W_ + w4];
            acc[0][0] = dot8(xv.x, wv.x, acc[0][0]); acc[0][1] = dot8(xv.y, wv.x, acc[0][1]);
            acc[0][2] = dot8(xv.z, wv.x, acc[0][2]); acc[0][3] = dot8(xv.w, wv.x, acc[0][3]);
            acc[1][0] = dot8(xv.x, wv.y, acc[1][0]); acc[1][1] = dot8(xv.y, wv.y, acc[1][1]);
            acc[1][2] = dot8(xv.z, wv.y, acc[1][2]); acc[1][3] = dot8(xv.w, wv.y, acc[1][3]);
            acc[2][0] = dot8(xv.x, wv.z, acc[2][0]); acc[2][1] = dot8(xv.y, wv.z, acc[2][1]);
            acc[2][2] = dot8(xv.z, wv.z, acc[2][2]); acc[2][3] = dot8(xv.w, wv.z, acc[2][3]);
            acc[3][0] = dot8(xv.x, wv.w, acc[3][0]); acc[3][1] = dot8(xv.y, wv.w, acc[3][1]);
            acc[3][2] = dot8(xv.z, wv.w, acc[3][2]); acc[3][3] = dot8(xv.w, wv.w, acc[3][3]);
        }
        float4 inv3v = *(const float4*)&bnb[1536 + 4 * coq];
        float4 bet3v = *(const float4*)&bnb[1632 + 4 * coq];
        float4 invSv = *(const float4*)&bnb[1728 + 4 * coq];
        float4 betSv = *(const float4*)&bnb[1824 + 4 * coq];
        float inv3a[4] = {inv3v.x, inv3v.y, inv3v.z, inv3v.w};
        float bet3a[4] = {bet3v.x, bet3v.y, bet3v.z, bet3v.w};
        float invSa[4] = {invSv.x, invSv.y, invSv.z, invSv.w};
        float betSa[4] = {betSv.x, betSv.y, betSv.z, betSv.w};
#pragma unroll
        for (int c = 0; c < 4; c++) {
            int co = coq * 4 + c;
            size_t idx = (size_t)(b * CO_ + co) * HW_ + h * W_ + w4;
            short4 c3 = *(const short4*)(acc3 + idx);
            int c3a[4] = {c3.x, c3.y, c3.z, c3.w};
            float4 o4;
            float* o = (float*)&o4;
#pragma unroll
            for (int j = 0; j < 4; j++) {
                int q3 = iclamp((int)rintf(__fmul_rn((float)c3a[j], rq3)), -128, 127);
                float y3 = __fadd_rn(__fmul_rn(__fmul_rn((float)q3, s_q3), inv3a[c]), bet3a[c]);
                int qs = iclamp((int)rintf(__fmul_rn((float)acc[c][j], rqs)), -8, 7);
                float ys = __fadd_rn(__fmul_rn(__fmul_rn((float)qs, s_qs), invSa[c]), betSa[c]);
                float oo = __fadd_rn(y3, ys);
                int L = iclamp((int)rintf(__fmul_rn(oo, 4.f)), 0, 15);
                o[j] = (float)L * 0.25f;
            }
            *(float4*)(dout + idx) = o4;
        }
    }
}

extern "C" void kernel_launch(void* const* d_in, const int* in_sizes, int n_in,
                              void* d_out, int out_size, void* d_ws, size_t ws_size,
                              hipStream_t stream)
{
    const float* x   = (const float*)d_in[0];
    const float* w1  = (const float*)d_in[1];
    const float* g1  = (const float*)d_in[2];
    const float* b1  = (const float*)d_in[3];
    const float* m1  = (const float*)d_in[4];
    const float* v1  = (const float*)d_in[5];
    const float* w2  = (const float*)d_in[6];
    const float* g2  = (const float*)d_in[7];
    const float* b2  = (const float*)d_in[8];
    const float* m2  = (const float*)d_in[9];
    const float* v2  = (const float*)d_in[10];
    const float* w3  = (const float*)d_in[11];
    const float* g3  = (const float*)d_in[12];
    const float* b3  = (const float*)d_in[13];
    const float* m3  = (const float*)d_in[14];
    const float* v3  = (const float*)d_in[15];
    const float* wsc = (const float*)d_in[16];
    const float* gs  = (const float*)d_in[17];
    const float* bs  = (const float*)d_in[18];
    const float* ms  = (const float*)d_in[19];
    const float* vs  = (const float*)d_in[20];

    // workspace layout (non-overlapping):
    //   0      sf (256B)          [memset 0]
    //   256    bnb (7680B)
    //   8192   w1n (12KB)
    //   32768  w2q (3.4KB)
    //   36864  w3n (18KB)
    //   73728  wsn (3KB)
    //   102400 smax (4KB)         [memset 0]
    //   1MB    xq4 (3.2MB)
    //   8MB    out1h / acc3 alias (19.3MB)
    //   48MB   out2h (19.3MB)
    char* ws = (char*)d_ws;
    float*   sf    = (float*)ws;
    float*   bnb   = (float*)(ws + 256);
    int*     w1n   = (int*)(ws + 8192);
    int8_t*  w2q   = (int8_t*)(ws + 32768);
    int*     w3n   = (int*)(ws + 36864);
    int*     wsn   = (int*)(ws + 73728);
    int*     smax  = (int*)(ws + 102400);
    int*     xq4   = (int*)(ws + (1u << 20));
    u16*     out1h = (u16*)(ws + (8u << 20));
    int16_t* acc3  = (int16_t*)(ws + (8u << 20));   // aliases out1h (dead after conv2)
    u16*     out2h = (u16*)(ws + (48u << 20));

    hipMemsetAsync(sf, 0, 256, stream);
    hipMemsetAsync(smax, 0, 4096, stream);
    k_maxes<<<XBLK + 8, 256, 0, stream>>>(x, w1, w2, w3, wsc, sf, bnb,
                                          g1, b1, m1, v1, g2, b2, m2, v2,
                                          g3, b3, m3, v3, gs, bs, ms, vs);
    k_quantw<<<47, 256, 0, stream>>>(w1, w2, w3, wsc, sf, w1n, w2q, w3n, wsn);
    k_conv1<<<B_ * 28, 192, 0, stream>>>(x, (const int4*)w1n, (const int4*)wsn,
                                         sf, bnb, out1h, xq4, smax);
    k_conv2<<<B_ * 96, 256, 0, stream>>>(out1h, w2q, sf, smax, bnb, out2h);
    k_conv3<<<B_ * 28, 256, 0, stream>>>(out2h, (const int4*)w3n, sf, smax, acc3);
    k_final<<<B_ * H_, 256, 0, stream>>>(xq4, (const int4*)wsn, acc3, sf, smax, bnb,
                                         (float*)d_out);
}

// Round 11
// 261.167 us; speedup vs baseline: 1.0336x; 1.0336x over previous
//
#include <hip/hip_runtime.h>
#include <stdint.h>

#define B_  32
#define CIN 64
#define H_  56
#define W_  56
#define HW_ 3136
#define P_  384
#define CO_ 96

typedef unsigned short u16;
typedef short v2s __attribute__((ext_vector_type(2)));

__device__ __forceinline__ v2s as_v2s(int x) {
    union { int i; v2s v; } u; u.i = x; return u.v;
}

// exp2(ceil(log2(max(m,1e-8)/n))) computed exactly (handles pot boundary via frexp)
__device__ __forceinline__ float pot_scale(float m, float n) {
    float q = fmaxf(m, 1e-8f) / n;
    int e; float f = frexpf(q, &e);        // q = f*2^e, f in [0.5,1)
    return ldexpf(1.0f, (f == 0.5f) ? (e - 1) : e);
}

// signed 8x int4 dot product (v_dot8_i32_i4)
__device__ __forceinline__ int dot8(int a, int b, int c) {
#if __has_builtin(__builtin_amdgcn_sdot8)
    return __builtin_amdgcn_sdot8(a, b, c, false);
#else
#pragma unroll
    for (int j = 0; j < 8; j++) {
        int av = (a << (28 - 4 * j)) >> 28;
        int bv = (b << (28 - 4 * j)) >> 28;
        c += av * bv;
    }
    return c;
#endif
}

__device__ __forceinline__ int iclamp(int v, int lo, int hi) { return min(max(v, lo), hi); }

// 16-entry level->level LUT (q = min(rint(L*r),7)) packed into two regs, 4b/entry.
__device__ __forceinline__ unsigned build_lut(float r, int lo) {
    unsigned v = 0;
#pragma unroll
    for (int L = 0; L < 8; L++)
        v |= (unsigned)min((int)rintf(__fmul_rn((float)(lo + L), r)), 7) << (4 * L);
    return v;
}
__device__ __forceinline__ int lut1(unsigned lo, unsigned hi, int L) {
    unsigned sel = (L & 8) ? hi : lo;
    return (int)((sel >> ((L & 7) * 4)) & 7u);
}

__device__ __forceinline__ int wave_max(int v) {
#pragma unroll
    for (int off = 32; off > 0; off >>= 1) v = max(v, __shfl_xor(v, off, 64));
    return v;
}
// block max over nw waves (v >= 0); red has >= (slot+1)*8 slots; 1 barrier
__device__ __forceinline__ int block_max_w(int v, int* red, int slot, int nw) {
    v = wave_max(v);
    int wid = threadIdx.x >> 6;
    if ((threadIdx.x & 63) == 0) red[slot * 8 + wid] = v;
    __syncthreads();
    int r = red[slot * 8];
#pragma unroll 4
    for (int i = 1; i < nw; i++) r = max(r, red[slot * 8 + i]);
    return r;
}

// sf[0]=max|x|, sf[1..4]=max|w1,w2,w3,ws|   (zeroed by hipMemsetAsync)
// smax (4KB, zeroed): quantity q at smax[q*256 + slot*16], slot in [0,16)
//   q=0: maxL1   q=1: maxL2   q=2: maxAcc3   q=3: maxAccS
#define SMAX_RD(sm, q, dst) { dst = 0; _Pragma("unroll") \
    for (int s_ = 0; s_ < 16; s_++) dst = max(dst, (sm)[(q) * 256 + s_ * 16]); }

#define XBLK 384
// x/w abs-max scan + BN constant precompute (bn blocks are independent of sf)
// bnb: inv1[0:384] beta1[384:768] inv2[768:1152] beta2[1152:1536]
//      inv3[1536:1632] beta3[1632:1728] invs[1728:1824] betas[1824:1920]
__global__ __launch_bounds__(256) void k_maxes(
    const float* __restrict__ x, const float* __restrict__ w1,
    const float* __restrict__ w2, const float* __restrict__ w3,
    const float* __restrict__ wsc, float* sf, float* bnb,
    const float* g1, const float* b1, const float* m1, const float* v1,
    const float* g2, const float* b2, const float* m2, const float* v2,
    const float* g3, const float* b3, const float* m3, const float* v3,
    const float* gs, const float* bs, const float* ms, const float* vs)
{
    __shared__ int red[16];
    int tid = threadIdx.x;
    if (blockIdx.x >= XBLK + 4) {                    // 4 bn-init blocks
        int t = (blockIdx.x - XBLK - 4) * 256 + tid; // 0..1023
        if (t < 384) {
            float inv = __fmul_rn(g1[t], __fdiv_rn(1.0f, sqrtf(__fadd_rn(v1[t], 1e-5f))));
            bnb[t] = inv;
            bnb[384 + t] = __fsub_rn(b1[t], __fmul_rn(m1[t], inv));
        } else if (t < 768) {
            int i = t - 384;
            float inv = __fmul_rn(g2[i], __fdiv_rn(1.0f, sqrtf(__fadd_rn(v2[i], 1e-5f))));
            bnb[768 + i] = inv;
            bnb[1152 + i] = __fsub_rn(b2[i], __fmul_rn(m2[i], inv));
        } else if (t < 864) {
            int i = t - 768;
            float inv = __fmul_rn(g3[i], __fdiv_rn(1.0f, sqrtf(__fadd_rn(v3[i], 1e-5f))));
            bnb[1536 + i] = inv;
            bnb[1632 + i] = __fsub_rn(b3[i], __fmul_rn(m3[i], inv));
        } else if (t < 960) {
            int i = t - 864;
            float inv = __fmul_rn(gs[i], __fdiv_rn(1.0f, sqrtf(__fadd_rn(vs[i], 1e-5f))));
            bnb[1728 + i] = inv;
            bnb[1824 + i] = __fsub_rn(bs[i], __fmul_rn(ms[i], inv));
        }
        return;
    }
    float m = 0.f;
    if (blockIdx.x < XBLK) {
        const float4* x4 = (const float4*)x;
        const int n4 = (B_ * CIN * HW_) / 4;   // 1605632
        for (int i = blockIdx.x * 256 + tid; i < n4; i += XBLK * 256) {
            float4 v = x4[i];
            m = fmaxf(m, fmaxf(fmaxf(fabsf(v.x), fabsf(v.y)),
                               fmaxf(fabsf(v.z), fabsf(v.w))));
        }
        int bm = block_max_w(__float_as_int(m), red, 0, 4);
        if (tid == 0) atomicMax((int*)&sf[0], bm);
    } else {
        int seg = blockIdx.x - XBLK;
        const float* p = seg == 0 ? w1 : seg == 1 ? w2 : seg == 2 ? w3 : wsc;
        int n = seg == 0 ? P_ * CIN : seg == 1 ? P_ * 9 : seg == 2 ? CO_ * P_ : CO_ * CIN;
        for (int i = tid; i < n; i += 256) m = fmaxf(m, fabsf(p[i]));
        int bm = block_max_w(__float_as_int(m), red, 0, 4);
        if (tid == 0) atomicMax((int*)&sf[1 + seg], bm);
    }
}

// weight quant + nibble repack (layouts unchanged)
__global__ __launch_bounds__(256) void k_quantw(
    const float* __restrict__ w1, const float* __restrict__ w2,
    const float* __restrict__ w3, const float* __restrict__ wsc,
    const float* __restrict__ sf,
    int* __restrict__ w1n, int8_t* __restrict__ w2q,
    int* __restrict__ w3n, int* __restrict__ wsn)
{
    int flat = blockIdx.x * 256 + threadIdx.x;
    if (flat < 3072) {                               // w1n
        int d = flat, co = d & 3, k8 = (d >> 2) & 7, g = d >> 5;
        float r = 1.0f / pot_scale(sf[1], 7.f);
        const float* src = w1 + (4 * g + co) * 64 + 8 * k8;
        unsigned pk = 0;
#pragma unroll
        for (int j = 0; j < 8; j++) {
            int q = iclamp((int)rintf(__fmul_rn(src[j], r)), -8, 7);
            pk |= (unsigned)(q & 0xF) << (4 * j);
        }
        w1n[d] = (int)pk;
    } else if (flat < 7680) {                        // w3n
        int d = flat - 3072, co = d & 3, k8 = (d >> 2) % 48, coq = d / 192;
        float r = 1.0f / pot_scale(sf[3], 7.f);
        const float* src = w3 + (4 * coq + co) * 384 + 8 * k8;
        unsigned pk = 0;
#pragma unroll
        for (int j = 0; j < 8; j++) {
            int q = iclamp((int)rintf(__fmul_rn(src[j], r)), -8, 7);
            pk |= (unsigned)(q & 0xF) << (4 * j);
        }
        w3n[d] = (int)pk;
    } else if (flat < 8448) {                        // wsn
        int d = flat - 7680, co = d & 3, k8 = (d >> 2) & 7, coq = d >> 5;
        float r = 1.0f / pot_scale(sf[4], 7.f);
        const float* src = wsc + (4 * coq + co) * 64 + 8 * k8;
        unsigned pk = 0;
#pragma unroll
        for (int j = 0; j < 8; j++) {
            int q = iclamp((int)rintf(__fmul_rn(src[j], r)), -8, 7);
            pk |= (unsigned)(q & 0xF) << (4 * j);
        }
        wsn[d] = (int)pk;
    } else if (flat < 11904) {                       // w2: [384*9] int8
        int i = flat - 8448;
        float r = 1.0f / pot_scale(sf[2], 7.f);
        w2q[i] = (int8_t)iclamp((int)rintf(__fmul_rn(w2[i], r)), -8, 7);
    }
}

// expand 1x1 (64->384) + BN1 + QuantReLU4 -> nibble-level out1h[b][96][hw] (u16 = 4ch)
// Fused: x quantization (emits xq4 for k_final) + shortcut amax. (R9 structure)
__global__ __launch_bounds__(192) void k_conv1(
    const float* __restrict__ x, const int4* __restrict__ w1n,
    const int4* __restrict__ wsn,
    const float* __restrict__ sf, const float* __restrict__ bnb,
    u16* __restrict__ out1h, int* __restrict__ xq4, int* smax)
{
    __shared__ __align__(16) int xs[8 * W_];
    __shared__ __align__(16) u16 otile[96 * W_];     // 10.5KB
    __shared__ int red[16];
    int tid = threadIdx.x;
    int b = blockIdx.x / H_, h = blockIdx.x % H_;
    float rx = 1.0f / pot_scale(sf[0], 7.0f);
    for (int i = tid; i < 8 * W_; i += 192) {        // 448 tasks: (c8, w)
        int c8 = i / W_, w = i % W_;
        const float* xp = x + (size_t)(b * 64 + c8 * 8) * HW_ + h * W_ + w;
        unsigned pk = 0;
#pragma unroll
        for (int j = 0; j < 8; j++) {
            int q = iclamp((int)rintf(__fmul_rn(xp[(size_t)j * HW_], rx)), -8, 7);
            pk |= (unsigned)(q & 0xF) << (4 * j);
        }
        xs[i] = (int)pk;
        xq4[(size_t)(b * 8 + c8) * HW_ + h * W_ + w] = (int)pk;
    }
    float sprod = __fmul_rn(pot_scale(sf[0], 7.f), pot_scale(sf[1], 7.f));
    __syncthreads();
    int g = tid % 96, half = tid / 96;               // half in {0,1}
    int4 wreg[8];
    {
        const int4* wp = w1n + g * 8;
#pragma unroll
        for (int k = 0; k < 8; k++) wreg[k] = wp[k];
    }
    float4 invv = *(const float4*)&bnb[4 * g];
    float4 betv = *(const float4*)&bnb[384 + 4 * g];
    float inva[4] = {invv.x, invv.y, invv.z, invv.w};
    float beta[4] = {betv.x, betv.y, betv.z, betv.w};
    int lmax = 0;
#pragma unroll
    for (int q = 0; q < 7; q++) {
        int w4 = half * 28 + q * 4;
        int acc[4][4];                               // [co][w]
#pragma unroll
        for (int c = 0; c < 4; c++)
#pragma unroll
            for (int w = 0; w < 4; w++) acc[c][w] = 0;
#pragma unroll
        for (int k = 0; k < 8; k++) {
            int4 wv = wreg[k];
            int4 xv = *(const int4*)&xs[k * W_ + w4];
            acc[0][0] = dot8(xv.x, wv.x, acc[0][0]); acc[0][1] = dot8(xv.y, wv.x, acc[0][1]);
            acc[0][2] = dot8(xv.z, wv.x, acc[0][2]); acc[0][3] = dot8(xv.w, wv.x, acc[0][3]);
            acc[1][0] = dot8(xv.x, wv.y, acc[1][0]); acc[1][1] = dot8(xv.y, wv.y, acc[1][1]);
            acc[1][2] = dot8(xv.z, wv.y, acc[1][2]); acc[1][3] = dot8(xv.w, wv.y, acc[1][3]);
            acc[2][0] = dot8(xv.x, wv.z, acc[2][0]); acc[2][1] = dot8(xv.y, wv.z, acc[2][1]);
            acc[2][2] = dot8(xv.z, wv.z, acc[2][2]); acc[2][3] = dot8(xv.w, wv.z, acc[2][3]);
            acc[3][0] = dot8(xv.x, wv.w, acc[3][0]); acc[3][1] = dot8(xv.y, wv.w, acc[3][1]);
            acc[3][2] = dot8(xv.z, wv.w, acc[3][2]); acc[3][3] = dot8(xv.w, wv.w, acc[3][3]);
        }
        unsigned lv[4];
#pragma unroll
        for (int w = 0; w < 4; w++) {
            unsigned pkd = 0;
#pragma unroll
            for (int c = 0; c < 4; c++) {
                float y = __fadd_rn(__fmul_rn(__fmul_rn((float)acc[c][w], sprod), inva[c]), beta[c]);
                int L = iclamp((int)rintf(__fmul_rn(y, 4.f)), 0, 15);
                lmax = max(lmax, L);
                pkd |= (unsigned)L << (4 * c);
            }
            lv[w] = pkd;
        }
        *(uint2*)&otile[g * W_ + w4] =
            make_uint2(lv[0] | (lv[1] << 16), lv[2] | (lv[3] << 16));
    }
    __syncthreads();
    // cooperative coalesced store: 7 lanes cover one g row (112B)
    {
        u16* baseo = out1h + (size_t)(b * 96) * HW_ + h * W_;
        for (int i = tid; i < 96 * 7; i += 192) {
            int gg = i / 7, wq = (i % 7) * 8;
            *(uint4*)(baseo + (size_t)gg * HW_ + wq) = *(uint4*)&otile[gg * W_ + wq];
        }
    }
    int bm = block_max_w(lmax, red, 0, 3);
    if (tid == 0) atomicMax(&smax[0 * 256 + (blockIdx.x & 15) * 16], bm);
    // fused shortcut 1x1 amax (values recomputed in k_final)
    int amax = 0;
    for (int qi = tid; qi < 336; qi += 192) {
        int coq = qi / 14, w4 = (qi % 14) * 4;
        int acc[4][4];
#pragma unroll
        for (int c = 0; c < 4; c++)
#pragma unroll
            for (int w = 0; w < 4; w++) acc[c][w] = 0;
        const int4* wp = wsn + coq * 8;
#pragma unroll
        for (int k = 0; k < 8; k++) {
            int4 wv = wp[k];
            int4 xv = *(const int4*)&xs[k * W_ + w4];
            acc[0][0] = dot8(xv.x, wv.x, acc[0][0]); acc[0][1] = dot8(xv.y, wv.x, acc[0][1]);
            acc[0][2] = dot8(xv.z, wv.x, acc[0][2]); acc[0][3] = dot8(xv.w, wv.x, acc[0][3]);
            acc[1][0] = dot8(xv.x, wv.y, acc[1][0]); acc[1][1] = dot8(xv.y, wv.y, acc[1][1]);
            acc[1][2] = dot8(xv.z, wv.y, acc[1][2]); acc[1][3] = dot8(xv.w, wv.y, acc[1][3]);
            acc[2][0] = dot8(xv.x, wv.z, acc[2][0]); acc[2][1] = dot8(xv.y, wv.z, acc[2][1]);
            acc[2][2] = dot8(xv.z, wv.z, acc[2][2]); acc[2][3] = dot8(xv.w, wv.z, acc[2][3]);
            acc[3][0] = dot8(xv.x, wv.w, acc[3][0]); acc[3][1] = dot8(xv.y, wv.w, acc[3][1]);
            acc[3][2] = dot8(xv.z, wv.w, acc[3][2]); acc[3][3] = dot8(xv.w, wv.w, acc[3][3]);
        }
#pragma unroll
        for (int c = 0; c < 4; c++)
            amax = max(amax, max(max(abs(acc[c][0]), abs(acc[c][1])),
                                 max(abs(acc[c][2]), abs(acc[c][3]))));
    }
    bm = block_max_w(amax, red, 1, 3);
    if (tid == 0) atomicMax(&smax[3 * 256 + (blockIdx.x & 15) * 16], bm);
}

// depthwise 3x3 + BN2 + QuantReLU4; packed-i16 channel-pair MACs (v_pk ops)
__global__ __launch_bounds__(256) void k_conv2(
    const u16* __restrict__ out1h, const int8_t* __restrict__ w2q,
    const float* __restrict__ sf, int* smax,
    const float* __restrict__ bnb, u16* __restrict__ out2h)
{
    __shared__ int blut[256];                        // byte -> packed pair (i16 lanes)
    __shared__ __align__(8) int plane2[58 * 58 * 2]; // 26.9KB: [pix][pair]
    __shared__ int red[16];
    int tid = threadIdx.x;
    int b = blockIdx.x / 96, g = blockIdx.x % 96;
    int mL1; SMAX_RD(smax, 0, mL1);
    float s_a2 = pot_scale(0.25f * (float)mL1, 7.f);
    float r2 = 0.25f / s_a2;                         // exact pot ratio
    float sprod = __fmul_rn(s_a2, pot_scale(sf[2], 7.f));
    unsigned lutlo = build_lut(r2, 0), luthi = build_lut(r2, 8);
    blut[tid] = (lut1(lutlo, luthi, tid & 0xF) & 0xFFFF)
              | (lut1(lutlo, luthi, tid >> 4) << 16);
    int wv[4][9];
#pragma unroll
    for (int c = 0; c < 4; c++)
#pragma unroll
        for (int t = 0; t < 9; t++) wv[c][t] = (int)w2q[(4 * g + c) * 9 + t];
    int wpk[2][9];
#pragma unroll
    for (int p = 0; p < 2; p++)
#pragma unroll
        for (int t = 0; t < 9; t++)
            wpk[p][t] = (wv[2 * p][t] & 0xFFFF) | (wv[2 * p + 1][t] << 16);
    float4 invv = *(const float4*)&bnb[768 + 4 * g];
    float4 betv = *(const float4*)&bnb[1152 + 4 * g];
    float inva[4] = {invv.x, invv.y, invv.z, invv.w};
    float beta[4] = {betv.x, betv.y, betv.z, betv.w};
    __syncthreads();
    const u16* src = out1h + (size_t)(b * 96 + g) * HW_;
    for (int i = tid; i < 58 * 58; i += 256) {
        int r = i / 58, c = i % 58;
        int pv0 = 0, pv1 = 0;
        if (r >= 1 && r <= 56 && c >= 1 && c <= 56) {
            unsigned v = src[(r - 1) * W_ + (c - 1)];
            pv0 = blut[v & 0xFFu];
            pv1 = blut[(v >> 8) & 0xFFu];
        }
        *(int2*)&plane2[2 * i] = make_int2(pv0, pv1);
    }
    __syncthreads();
    int lmax = 0;
    int ow = tid & 63, seg = tid >> 6;               // 4 segs x 14 rows
    if (ow < 56) {
        int oh0 = seg * 14;
        const int2* pl = (const int2*)plane2;
        u16* dst = out2h + (size_t)(b * 96 + g) * HW_ + ow;
        int2 p00 = pl[oh0 * 58 + ow],       p01 = pl[oh0 * 58 + ow + 1],       p02 = pl[oh0 * 58 + ow + 2];
        int2 p10 = pl[(oh0 + 1) * 58 + ow], p11 = pl[(oh0 + 1) * 58 + ow + 1], p12 = pl[(oh0 + 1) * 58 + ow + 2];
#pragma unroll 2
        for (int oh = oh0; oh < oh0 + 14; oh++) {
            int2 p20 = pl[(oh + 2) * 58 + ow], p21 = pl[(oh + 2) * 58 + ow + 1],
                 p22 = pl[(oh + 2) * 58 + ow + 2];
            v2s a0 = as_v2s(p00.x) * as_v2s(wpk[0][0]);
            a0 += as_v2s(p01.x) * as_v2s(wpk[0][1]);
            a0 += as_v2s(p02.x) * as_v2s(wpk[0][2]);
            a0 += as_v2s(p10.x) * as_v2s(wpk[0][3]);
            a0 += as_v2s(p11.x) * as_v2s(wpk[0][4]);
            a0 += as_v2s(p12.x) * as_v2s(wpk[0][5]);
            a0 += as_v2s(p20.x) * as_v2s(wpk[0][6]);
            a0 += as_v2s(p21.x) * as_v2s(wpk[0][7]);
            a0 += as_v2s(p22.x) * as_v2s(wpk[0][8]);
            v2s a1 = as_v2s(p00.y) * as_v2s(wpk[1][0]);
            a1 += as_v2s(p01.y) * as_v2s(wpk[1][1]);
            a1 += as_v2s(p02.y) * as_v2s(wpk[1][2]);
            a1 += as_v2s(p10.y) * as_v2s(wpk[1][3]);
            a1 += as_v2s(p11.y) * as_v2s(wpk[1][4]);
            a1 += as_v2s(p12.y) * as_v2s(wpk[1][5]);
            a1 += as_v2s(p20.y) * as_v2s(wpk[1][6]);
            a1 += as_v2s(p21.y) * as_v2s(wpk[1][7]);
            a1 += as_v2s(p22.y) * as_v2s(wpk[1][8]);
            int acca[4] = {(int)a0.x, (int)a0.y, (int)a1.x, (int)a1.y};
            unsigned pkd = 0;
#pragma unroll
            for (int c = 0; c < 4; c++) {
                float y = __fadd_rn(__fmul_rn(__fmul_rn((float)acca[c], sprod), inva[c]), beta[c]);
                int L = iclamp((int)rintf(__fmul_rn(y, 4.f)), 0, 15);
                lmax = max(lmax, L);
                pkd |= (unsigned)L << (4 * c);
            }
            dst[oh * W_] = (u16)pkd;
            p00 = p10; p01 = p11; p02 = p12;
            p10 = p20; p11 = p21; p12 = p22;
        }
    }
    int bm = block_max_w(lmax, red, 0, 4);
    if (tid == 0) atomicMax(&smax[1 * 256 + (blockIdx.x & 15) * 16], bm);
}

// project 1x1 (384->96): nibble dot8; 2 rows/block; int16 acc out
__global__ __launch_bounds__(256) void k_conv3(
    const u16* __restrict__ out2h, const int4* __restrict__ w3n,
    const float* __restrict__ sf, int* smax,
    int16_t* __restrict__ acc3)
{
    __shared__ __align__(16) int a3s[2 * 48 * W_];   // 21.5KB nibble-packed
    __shared__ int nlut[256];                        // byte -> 2 quant nibbles
    __shared__ int red[16];
    int tid = threadIdx.x;
    int b = blockIdx.x / 28, h0 = (blockIdx.x % 28) * 2;
    int mL2; SMAX_RD(smax, 1, mL2);
    float s_a3 = pot_scale(0.25f * (float)mL2, 7.f);
    float r3 = 0.25f / s_a3;
    unsigned lutlo = build_lut(r3, 0), luthi = build_lut(r3, 8);
    nlut[tid] = lut1(lutlo, luthi, tid & 0xF) | (lut1(lutlo, luthi, tid >> 4) << 4);
    __syncthreads();
    for (int i = tid; i < 2 * 48 * W_; i += 256) {   // 5376 = 21*256 exact
        int row = i / (48 * W_), rem = i % (48 * W_), c8 = rem / W_, w = rem % W_;
        size_t base = (size_t)(b * 96 + c8 * 2) * HW_ + (h0 + row) * W_ + w;
        unsigned v0 = out2h[base], v1 = out2h[base + HW_];
        unsigned q0 = (unsigned)nlut[v0 & 0xFFu] | ((unsigned)nlut[(v0 >> 8) & 0xFFu] << 8);
        unsigned q1 = (unsigned)nlut[v1 & 0xFFu] | ((unsigned)nlut[(v1 >> 8) & 0xFFu] << 8);
        a3s[i] = (int)(q0 | (q1 << 16));
    }
    __syncthreads();
    int amax = 0;
    for (int qi = tid; qi < 672; qi += 256) {        // coq(24) x row(2) x w4(14)
        int coq = qi / 28, rem2 = qi % 28, row = rem2 / 14, w4 = (rem2 % 14) * 4;
        int acc[4][4];                               // [co][w]
#pragma unroll
        for (int c = 0; c < 4; c++)
#pragma unroll
            for (int w = 0; w < 4; w++) acc[c][w] = 0;
        const int4* wp = w3n + coq * 48;
        const int* ap = a3s + row * 48 * W_ + w4;
#pragma unroll 6
        for (int k = 0; k < 48; k++) {
            int4 wv = wp[k];
            int4 av = *(const int4*)(ap + k * W_);
            acc[0][0] = dot8(av.x, wv.x, acc[0][0]); acc[0][1] = dot8(av.y, wv.x, acc[0][1]);
            acc[0][2] = dot8(av.z, wv.x, acc[0][2]); acc[0][3] = dot8(av.w, wv.x, acc[0][3]);
            acc[1][0] = dot8(av.x, wv.y, acc[1][0]); acc[1][1] = dot8(av.y, wv.y, acc[1][1]);
            acc[1][2] = dot8(av.z, wv.y, acc[1][2]); acc[1][3] = dot8(av.w, wv.y, acc[1][3]);
            acc[2][0] = dot8(av.x, wv.z, acc[2][0]); acc[2][1] = dot8(av.y, wv.z, acc[2][1]);
            acc[2][2] = dot8(av.z, wv.z, acc[2][2]); acc[2][3] = dot8(av.w, wv.z, acc[2][3]);
            acc[3][0] = dot8(av.x, wv.w, acc[3][0]); acc[3][1] = dot8(av.y, wv.w, acc[3][1]);
            acc[3][2] = dot8(av.z, wv.w, acc[3][2]); acc[3][3] = dot8(av.w, wv.w, acc[3][3]);
        }
#pragma unroll
        for (int c = 0; c < 4; c++) {
            int co = coq * 4 + c;
            amax = max(amax, max(max(abs(acc[c][0]), abs(acc[c][1])),
                                 max(abs(acc[c][2]), abs(acc[c][3]))));
            short4 st = make_short4((short)acc[c][0], (short)acc[c][1],
                                    (short)acc[c][2], (short)acc[c][3]);
            *(short4*)(acc3 + (size_t)(b * CO_ + co) * HW_ + (h0 + row) * W_ + w4) = st;
        }
    }
    int bm = block_max_w(amax, red, 0, 4);
    if (tid == 0) atomicMax(&smax[2 * 256 + (blockIdx.x & 15) * 16], bm);
}

// fq8(conv3)+BN3 + fq4(shortcut)+BNs + add + QuantReLU4 -> fp32 out
__global__ __launch_bounds__(256) void k_final(
    const int* __restrict__ xq4, const int4* __restrict__ wsn,
    const int16_t* __restrict__ acc3, const float* __restrict__ sf,
    const int* __restrict__ smax, const float* __restrict__ bnb,
    float* __restrict__ dout)
{
    __shared__ __align__(16) int xs[8 * W_];
    int tid = threadIdx.x;
    int b = blockIdx.x / H_, h = blockIdx.x % H_;
    for (int i = tid; i < 8 * W_; i += 256)
        xs[i] = xq4[((b * 8 + i / W_) * HW_) + h * W_ + (i % W_)];
    int mL2, mA3, mAS;
    SMAX_RD(smax, 1, mL2); SMAX_RD(smax, 2, mA3); SMAX_RD(smax, 3, mAS);
    float s_a3   = pot_scale(0.25f * (float)mL2, 7.f);
    float sprod3 = __fmul_rn(s_a3, pot_scale(sf[3], 7.f));
    float s_q3   = pot_scale(__fmul_rn(sprod3, (float)mA3), 127.f);
    float rq3    = sprod3 / s_q3;                    // exact pot ratio
    float sprods = __fmul_rn(pot_scale(sf[0], 7.f), pot_scale(sf[4], 7.f));
    float s_qs   = pot_scale(__fmul_rn(sprods, (float)mAS), 7.f);
    float rqs    = sprods / s_qs;
    __syncthreads();
    for (int qi = tid; qi < 24 * 14; qi += 256) {    // 336 tiles
        int coq = qi / 14, w4 = (qi % 14) * 4;
        int acc[4][4];
#pragma unroll
        for (int c = 0; c < 4; c++)
#pragma unroll
            for (int w = 0; w < 4; w++) acc[c][w] = 0;
        const int4* wp = wsn + coq * 8;
#pragma unroll
        for (int k = 0; k < 8; k++) {
            int4 wv = wp[k];
            int4 xv = *(const int4*)&xs[k * W_ + w4];
            acc[0][0] = dot8(xv.x, wv.x, acc[0][0]); acc[0][1] = dot8(xv.y, wv.x, acc[0][1]);
            acc[0][2] = dot8(xv.z, wv.x, acc[0][2]); acc[0][3] = dot8(xv.w, wv.x, acc[0][3]);
            acc[1][0] = dot8(xv.x, wv.y, acc[1][0]); acc[1][1] = dot8(xv.y, wv.y, acc[1][1]);
            acc[1][2] = dot8(xv.z, wv.y, acc[1][2]); acc[1][3] = dot8(xv.w, wv.y, acc[1][3]);
            acc[2][0] = dot8(xv.x, wv.z, acc[2][0]); acc[2][1] = dot8(xv.y, wv.z, acc[2][1]);
            acc[2][2] = dot8(xv.z, wv.z, acc[2][2]); acc[2][3] = dot8(xv.w, wv.z, acc[2][3]);
            acc[3][0] = dot8(xv.x, wv.w, acc[3][0]); acc[3][1] = dot8(xv.y, wv.w, acc[3][1]);
            acc[3][2] = dot8(xv.z, wv.w, acc[3][2]); acc[3][3] = dot8(xv.w, wv.w, acc[3][3]);
        }
        float4 inv3v = *(const float4*)&bnb[1536 + 4 * coq];
        float4 bet3v = *(const float4*)&bnb[1632 + 4 * coq];
        float4 invSv = *(const float4*)&bnb[1728 + 4 * coq];
        float4 betSv = *(const float4*)&bnb[1824 + 4 * coq];
        float inv3a[4] = {inv3v.x, inv3v.y, inv3v.z, inv3v.w};
        float bet3a[4] = {bet3v.x, bet3v.y, bet3v.z, bet3v.w};
        float invSa[4] = {invSv.x, invSv.y, invSv.z, invSv.w};
        float betSa[4] = {betSv.x, betSv.y, betSv.z, betSv.w};
#pragma unroll
        for (int c = 0; c < 4; c++) {
            int co = coq * 4 + c;
            size_t idx = (size_t)(b * CO_ + co) * HW_ + h * W_ + w4;
            short4 c3 = *(const short4*)(acc3 + idx);
            int c3a[4] = {c3.x, c3.y, c3.z, c3.w};
            float4 o4;
            float* o = (float*)&o4;
#pragma unroll
            for (int j = 0; j < 4; j++) {
                int q3 = iclamp((int)rintf(__fmul_rn((float)c3a[j], rq3)), -128, 127);
                float y3 = __fadd_rn(__fmul_rn(__fmul_rn((float)q3, s_q3), inv3a[c]), bet3a[c]);
                int qs = iclamp((int)rintf(__fmul_rn((float)acc[c][j], rqs)), -8, 7);
                float ys = __fadd_rn(__fmul_rn(__fmul_rn((float)qs, s_qs), invSa[c]), betSa[c]);
                float oo = __fadd_rn(y3, ys);
                int L = iclamp((int)rintf(__fmul_rn(oo, 4.f)), 0, 15);
                o[j] = (float)L * 0.25f;
            }
            *(float4*)(dout + idx) = o4;
        }
    }
}

extern "C" void kernel_launch(void* const* d_in, const int* in_sizes, int n_in,
                              void* d_out, int out_size, void* d_ws, size_t ws_size,
                              hipStream_t stream)
{
    const float* x   = (const float*)d_in[0];
    const float* w1  = (const float*)d_in[1];
    const float* g1  = (const float*)d_in[2];
    const float* b1  = (const float*)d_in[3];
    const float* m1  = (const float*)d_in[4];
    const float* v1  = (const float*)d_in[5];
    const float* w2  = (const float*)d_in[6];
    const float* g2  = (const float*)d_in[7];
    const float* b2  = (const float*)d_in[8];
    const float* m2  = (const float*)d_in[9];
    const float* v2  = (const float*)d_in[10];
    const float* w3  = (const float*)d_in[11];
    const float* g3  = (const float*)d_in[12];
    const float* b3  = (const float*)d_in[13];
    const float* m3  = (const float*)d_in[14];
    const float* v3  = (const float*)d_in[15];
    const float* wsc = (const float*)d_in[16];
    const float* gs  = (const float*)d_in[17];
    const float* bs  = (const float*)d_in[18];
    const float* ms  = (const float*)d_in[19];
    const float* vs  = (const float*)d_in[20];

    // workspace layout (non-overlapping):
    //   0      sf (256B)          [memset 0]
    //   256    bnb (7680B)
    //   8192   w1n (12KB)
    //   32768  w2q (3.4KB)
    //   36864  w3n (18KB)
    //   73728  wsn (3KB)
    //   102400 smax (4KB)         [memset 0]
    //   1MB    xq4 (3.2MB)
    //   8MB    out1h / acc3 alias (19.3MB)
    //   48MB   out2h (19.3MB)
    char* ws = (char*)d_ws;
    float*   sf    = (float*)ws;
    float*   bnb   = (float*)(ws + 256);
    int*     w1n   = (int*)(ws + 8192);
    int8_t*  w2q   = (int8_t*)(ws + 32768);
    int*     w3n   = (int*)(ws + 36864);
    int*     wsn   = (int*)(ws + 73728);
    int*     smax  = (int*)(ws + 102400);
    int*     xq4   = (int*)(ws + (1u << 20));
    u16*     out1h = (u16*)(ws + (8u << 20));
    int16_t* acc3  = (int16_t*)(ws + (8u << 20));   // aliases out1h (dead after conv2)
    u16*     out2h = (u16*)(ws + (48u << 20));

    hipMemsetAsync(sf, 0, 256, stream);
    hipMemsetAsync(smax, 0, 4096, stream);
    k_maxes<<<XBLK + 8, 256, 0, stream>>>(x, w1, w2, w3, wsc, sf, bnb,
                                          g1, b1, m1, v1, g2, b2, m2, v2,
                                          g3, b3, m3, v3, gs, bs, ms, vs);
    k_quantw<<<47, 256, 0, stream>>>(w1, w2, w3, wsc, sf, w1n, w2q, w3n, wsn);
    k_conv1<<<B_ * H_, 192, 0, stream>>>(x, (const int4*)w1n, (const int4*)wsn,
                                         sf, bnb, out1h, xq4, smax);
    k_conv2<<<B_ * 96, 256, 0, stream>>>(out1h, w2q, sf, smax, bnb, out2h);
    k_conv3<<<B_ * 28, 256, 0, stream>>>(out2h, (const int4*)w3n, sf, smax, acc3);
    k_final<<<B_ * H_, 256, 0, stream>>>(xq4, (const int4*)wsn, acc3, sf, smax, bnb,
                                         (float*)d_out);
}